// Round 9
// baseline (68.534 us; speedup 1.0000x reference)
//
#include <hip/hip_runtime.h>

typedef __attribute__((ext_vector_type(8))) short short8;
typedef __attribute__((ext_vector_type(4))) float floatx4;
typedef unsigned int uint;
typedef unsigned short ushort;

#define BATCH 16
#define CH 64
#define NPIX 16384   // 128*128
#define TWOC 128

__device__ __forceinline__ ushort f2bf(float f) {   // RNE f32 -> bf16 bits
    uint u = __float_as_uint(f);
    u += 0x7FFFu + ((u >> 16) & 1u);
    return (ushort)(u >> 16);
}
__device__ __forceinline__ uint pk2(float lo, float hi) {
    return (uint)f2bf(lo) | ((uint)f2bf(hi) << 16);
}

// async global->LDS DMA, 16B per lane (dest = wave-uniform base + lane*16)
typedef const __attribute__((address_space(1))) void gas_void;
typedef __attribute__((address_space(3))) void las_void;
__device__ __forceinline__ void gload16(const void* g, void* l) {
    __builtin_amdgcn_global_load_lds((gas_void*)g, (las_void*)l, 16, 0, 0);
}

// ---------------------------------------------------------------------------
// Kernel 1: partial Gram matrices G[b][map][64][64] = sum_n V[c,n]*V[d,n]
// Early-exits when the corresponding scalar is exactly 0 (algebraic
// short-circuit: contribution is exactly zero; still deterministic).
// ---------------------------------------------------------------------------
__global__ __launch_bounds__(256) void gram_kernel(
    const float* __restrict__ tmap, const float* __restrict__ rmap,
    const float* __restrict__ gamma, const float* __restrict__ omega,
    float* __restrict__ G)
{
    const int map = blockIdx.y;
    const float mult = (map == 0) ? omega[0] : gamma[0];
    if (mult == 0.f) return;   // wave-uniform: skip dead attention branch

    __shared__ float tile[64][68];
    const int chunk = blockIdx.x;
    const int b     = blockIdx.z;
    const float* x = (map == 0 ? tmap : rmap) + (size_t)b * CH * NPIX + chunk * 512;
    const int t  = threadIdx.x;
    const int ti = t >> 4;
    const int tj = t & 15;

    float acc[4][4];
#pragma unroll
    for (int i = 0; i < 4; ++i)
#pragma unroll
        for (int j = 0; j < 4; ++j) acc[i][j] = 0.f;

    for (int tt = 0; tt < 8; ++tt) {
        const int col0 = tt * 64;
#pragma unroll
        for (int k = 0; k < 16; ++k) {
            int e = t + 256 * k;
            int c = e >> 6, col = e & 63;
            tile[c][col] = x[(size_t)c * NPIX + col0 + col];
        }
        __syncthreads();
#pragma unroll 8
        for (int n = 0; n < 64; n += 2) {
            float2 av[4], bv[4];
#pragma unroll
            for (int i = 0; i < 4; ++i) av[i] = *(const float2*)&tile[ti + 16 * i][n];
#pragma unroll
            for (int j = 0; j < 4; ++j) bv[j] = *(const float2*)&tile[tj + 16 * j][n];
#pragma unroll
            for (int i = 0; i < 4; ++i)
#pragma unroll
                for (int j = 0; j < 4; ++j) {
                    acc[i][j] += av[i].x * bv[j].x;
                    acc[i][j] += av[i].y * bv[j].y;
                }
        }
        __syncthreads();
    }
    float* Gp = G + ((size_t)(b * 2 + map) << 12);
#pragma unroll
    for (int i = 0; i < 4; ++i)
#pragma unroll
        for (int j = 0; j < 4; ++j)
            atomicAdd(&Gp[(ti + 16 * i) * 64 + (tj + 16 * j)], acc[i][j]);
}

// ---------------------------------------------------------------------------
// Kernel 2: per-batch softmax + build mixing matrix, stored as bf16
// A-FRAGMENTS for mfma_f32_16x16x32_bf16:
//   flat idx = ((kstep*4 + mi)*64 + lane)*8 + e
//   holds M[mi*16 + (lane&15)][kstep*32 + (lane>>4)*8 + e]
// ---------------------------------------------------------------------------
__global__ __launch_bounds__(128) void finalize_kernel(
    const float* __restrict__ G, const float* __restrict__ gamma,
    const float* __restrict__ omega, const float* __restrict__ conv_w,
    ushort* __restrict__ Mtf)
{
    __shared__ float attn[2][64][64];
    const int b = blockIdx.x;
    const int t = threadIdx.x;
    const float gam = gamma[0], om = omega[0];
    {
        const int map = t >> 6, i = t & 63;
        const float need = (map == 0) ? om : gam;
        if (need != 0.f) {
            const float* Grow = G + ((size_t)(b * 2 + map) << 12) + i * 64;
            float mn = Grow[0];
            for (int j = 1; j < 64; ++j) mn = fminf(mn, Grow[j]);
            float s = 0.f;
            for (int j = 0; j < 64; ++j) s += expf(mn - Grow[j]);
            const float inv = 1.f / s;
            for (int j = 0; j < 64; ++j) attn[map][i][j] = expf(mn - Grow[j]) * inv;
        }
    }
    __syncthreads();
    for (int idx = t; idx < 8192; idx += 128) {
        const int e     = idx & 7;
        const int l     = (idx >> 3) & 63;
        const int mi    = (idx >> 9) & 3;
        const int kstep = idx >> 11;
        const int row = mi * 16 + (l & 15);
        const int k   = kstep * 32 + (l >> 4) * 8 + e;
        const float* wrow = conv_w + row * TWOC;
        float v = wrow[k];
        if (k < 64) {
            if (gam != 0.f) {
                float dot = 0.f;
                for (int c = 0; c < 64; ++c) dot += wrow[c] * attn[1][c][k];      // r_attn
                v += gam * dot;
            }
        } else {
            const int d = k - 64;
            if (om != 0.f) {
                float dot = 0.f;
                for (int c = 0; c < 64; ++c) dot += wrow[64 + c] * attn[0][c][d]; // t_attn
                v += om * dot;
            }
        }
        Mtf[(size_t)b * 8192 + idx] = f2bf(v);
    }
}

// ---------------------------------------------------------------------------
// Kernel 3 (MFMA + global_load_lds DMA staging + coalesced stores):
//   out[b](64 x 16384) = M[b](64x128) @ X(128x16384) + bias
// X rows 0..63 = template channels, 64..127 = roi channels.
//
// Block 256 thr = 4 waves, tile 64 och x 256 px, K in 4 chunks of 32 rows.
// Stage: per chunk, each wave issues 8 INDEPENDENT global_load_lds_dwordx4
//   (one full 1 KB px-row per instruction, f32, no dest regs, no dependent
//   pack chain) -> Xs[32][256] f32 (32 KB). No VGPR round-trip.
// Compute: A-frags direct per-lane 16B loads from fragment-ordered Mtf
//   (L2-hot); B-frags = 8 ds_read_b32 + read-side f32->bf16 pack; 16 MFMA.
// Epilogue: LDS transpose (reusing Xs) -> every global store is a 1 KB
//   coalesced dwordx4 row write (was: 64 B scattered granules).
// ---------------------------------------------------------------------------
__global__ __launch_bounds__(256, 4) void out_kernel(
    const float* __restrict__ tmap, const float* __restrict__ rmap,
    const ushort* __restrict__ Mtf, const float* __restrict__ conv_b,
    float* __restrict__ out)
{
    __shared__ __align__(16) uint Xs[32 * 256];   // 32 KB: f32 chunk tile [k][px]

    const int b   = blockIdx.y;
    const int t   = threadIdx.x;
    const int w   = t >> 6;
    const int l   = t & 63;
    const int lg  = l >> 4;
    const int lj  = l & 15;
    const int px0 = blockIdx.x * 256;

    const ushort* mbase = Mtf + (size_t)b * 8192;
    const float*  tb = tmap + (size_t)b * CH * NPIX + px0;
    const float*  rb = rmap + (size_t)b * CH * NPIX + px0;

    floatx4 acc[4][4];             // [mi][nj]
#pragma unroll
    for (int mi = 0; mi < 4; ++mi)
#pragma unroll
        for (int nj = 0; nj < 4; ++nj) acc[mi][nj] = (floatx4){0.f, 0.f, 0.f, 0.f};

#pragma unroll
    for (int c = 0; c < 4; ++c) {
        // chunk c: global k = c*32 .. c*32+31 (c<2: template rows, else roi)
        const float* src = ((c < 2) ? tb : rb) + (size_t)((c & 1) * 32) * NPIX;

        // DMA stage: wave w stages rows {i*4+w}, one 1KB row per instruction
#pragma unroll
        for (int i = 0; i < 8; ++i) {
            const int row = i * 4 + w;
            gload16(src + (size_t)row * NPIX + 4 * l, &Xs[row * 256]);
        }

        // A-fragments: 4 x 16B contiguous per lane (L2-hot, drained at barrier)
        short8 a[4];
#pragma unroll
        for (int mi = 0; mi < 4; ++mi)
            a[mi] = *(const short8*)&mbase[((c * 4 + mi) * 64 + l) * 8];

        __syncthreads();   // DMA complete + (c>0) prior reads done

#pragma unroll
        for (int nj = 0; nj < 4; ++nj) {
            const int pxl = w * 64 + nj * 16 + lj;
            float v[8];
#pragma unroll
            for (int e = 0; e < 8; ++e)
                v[e] = __uint_as_float(Xs[(8 * lg + e) * 256 + pxl]);
            uint4 bu;
            bu.x = pk2(v[0], v[1]);
            bu.y = pk2(v[2], v[3]);
            bu.z = pk2(v[4], v[5]);
            bu.w = pk2(v[6], v[7]);
            const short8 bb = *(const short8*)&bu;
#pragma unroll
            for (int mi = 0; mi < 4; ++mi)
                acc[mi][nj] = __builtin_amdgcn_mfma_f32_16x16x32_bf16(
                    a[mi], bb, acc[mi][nj], 0, 0, 0);
        }
        __syncthreads();   // reads done before next chunk's DMA overwrites
    }

    // epilogue: transpose via LDS (reuse Xs; 2 groups of 32 och in 2 halves)
    // acc[g][nj][r] = out och (g*16 + lg*4 + r), block px (w*64 + nj*16 + lj)
    uint* buf = Xs;   // [2][16][256] = 32 KB
#pragma unroll
    for (int pass = 0; pass < 2; ++pass) {
#pragma unroll
        for (int gh = 0; gh < 2; ++gh) {          // och groups 2*pass, 2*pass+1
            const int g = pass * 2 + gh;
#pragma unroll
            for (int nj = 0; nj < 4; ++nj)
#pragma unroll
                for (int r = 0; r < 4; ++r)
                    buf[(gh * 16 + lg * 4 + r) * 256 + w * 64 + nj * 16 + lj] =
                        __float_as_uint(acc[g][nj][r] + conv_b[g * 16 + lg * 4 + r]);
        }
        __syncthreads();  // buf visible (also: prior pass reads / k-loop reads done)
#pragma unroll
        for (int gh = 0; gh < 2; ++gh) {
            const int g = pass * 2 + gh;
#pragma unroll
            for (int j = 0; j < 4; ++j) {
                const int ol = w + 4 * j;          // och-local 0..15
                const uint4 val = *(const uint4*)&buf[(gh * 16 + ol) * 256 + 4 * l];
                *(uint4*)&out[((size_t)b * CH + g * 16 + ol) * NPIX + px0 + 4 * l] = val;
            }
        }
        if (pass == 0) __syncthreads();  // stores read buf before overwrite
    }
}

// ---------------------------------------------------------------------------
extern "C" void kernel_launch(void* const* d_in, const int* in_sizes, int n_in,
                              void* d_out, int out_size, void* d_ws, size_t ws_size,
                              hipStream_t stream) {
    const float* tmap   = (const float*)d_in[0];
    const float* rmap   = (const float*)d_in[1];
    const float* gamma  = (const float*)d_in[2];
    const float* omega  = (const float*)d_in[3];
    const float* conv_w = (const float*)d_in[4];
    const float* conv_b = (const float*)d_in[5];
    float* out = (float*)d_out;

    // ws layout: G [16][2][4096] fp32 (512 KiB), then Mtf [16][8192] bf16 (256 KiB)
    float*  G   = (float*)d_ws;
    ushort* Mtf = (ushort*)((char*)d_ws + (size_t)BATCH * 2 * 4096 * sizeof(float));

    hipMemsetAsync(d_ws, 0, (size_t)BATCH * 2 * 4096 * sizeof(float), stream);

    gram_kernel<<<dim3(32, 2, BATCH), 256, 0, stream>>>(tmap, rmap, gamma, omega, G);
    finalize_kernel<<<dim3(BATCH), 128, 0, stream>>>(G, gamma, omega, conv_w, Mtf);
    out_kernel<<<dim3(64, BATCH), 256, 0, stream>>>(tmap, rmap, Mtf, conv_b, out);
}

// Round 10
// 55.745 us; speedup vs baseline: 1.2294x; 1.2294x over previous
//
#include <hip/hip_runtime.h>

typedef __attribute__((ext_vector_type(8))) short short8;
typedef __attribute__((ext_vector_type(4))) float floatx4;
typedef unsigned int uint;
typedef unsigned short ushort;

#define BATCH 16
#define CH 64
#define NPIX 16384   // 128*128
#define TWOC 128

__device__ __forceinline__ ushort f2bf(float f) {   // RNE f32 -> bf16 bits
    uint u = __float_as_uint(f);
    u += 0x7FFFu + ((u >> 16) & 1u);
    return (ushort)(u >> 16);
}
__device__ __forceinline__ uint pk2(float lo, float hi) {
    return (uint)f2bf(lo) | ((uint)f2bf(hi) << 16);
}

// async global->LDS DMA, 16B per lane (dest = wave-uniform base + lane*16)
typedef const __attribute__((address_space(1))) void gas_void;
typedef __attribute__((address_space(3))) void las_void;
__device__ __forceinline__ void gload16(const void* g, void* l) {
    __builtin_amdgcn_global_load_lds((gas_void*)g, (las_void*)l, 16, 0, 0);
}

// ---------------------------------------------------------------------------
// Kernel 1: partial Gram matrices G[b][map][64][64] = sum_n V[c,n]*V[d,n]
// Early-exits when the corresponding scalar is exactly 0 (algebraic
// short-circuit: contribution is exactly zero; still deterministic).
// ---------------------------------------------------------------------------
__global__ __launch_bounds__(256) void gram_kernel(
    const float* __restrict__ tmap, const float* __restrict__ rmap,
    const float* __restrict__ gamma, const float* __restrict__ omega,
    float* __restrict__ G)
{
    const int map = blockIdx.y;
    const float mult = (map == 0) ? omega[0] : gamma[0];
    if (mult == 0.f) return;   // wave-uniform: skip dead attention branch

    __shared__ float tile[64][68];
    const int chunk = blockIdx.x;
    const int b     = blockIdx.z;
    const float* x = (map == 0 ? tmap : rmap) + (size_t)b * CH * NPIX + chunk * 512;
    const int t  = threadIdx.x;
    const int ti = t >> 4;
    const int tj = t & 15;

    float acc[4][4];
#pragma unroll
    for (int i = 0; i < 4; ++i)
#pragma unroll
        for (int j = 0; j < 4; ++j) acc[i][j] = 0.f;

    for (int tt = 0; tt < 8; ++tt) {
        const int col0 = tt * 64;
#pragma unroll
        for (int k = 0; k < 16; ++k) {
            int e = t + 256 * k;
            int c = e >> 6, col = e & 63;
            tile[c][col] = x[(size_t)c * NPIX + col0 + col];
        }
        __syncthreads();
#pragma unroll 8
        for (int n = 0; n < 64; n += 2) {
            float2 av[4], bv[4];
#pragma unroll
            for (int i = 0; i < 4; ++i) av[i] = *(const float2*)&tile[ti + 16 * i][n];
#pragma unroll
            for (int j = 0; j < 4; ++j) bv[j] = *(const float2*)&tile[tj + 16 * j][n];
#pragma unroll
            for (int i = 0; i < 4; ++i)
#pragma unroll
                for (int j = 0; j < 4; ++j) {
                    acc[i][j] += av[i].x * bv[j].x;
                    acc[i][j] += av[i].y * bv[j].y;
                }
        }
        __syncthreads();
    }
    float* Gp = G + ((size_t)(b * 2 + map) << 12);
#pragma unroll
    for (int i = 0; i < 4; ++i)
#pragma unroll
        for (int j = 0; j < 4; ++j)
            atomicAdd(&Gp[(ti + 16 * i) * 64 + (tj + 16 * j)], acc[i][j]);
}

// ---------------------------------------------------------------------------
// Kernel 2: per-batch softmax + build mixing matrix, stored as bf16
// A-FRAGMENTS for mfma_f32_16x16x32_bf16:
//   flat idx = ((kstep*4 + mi)*64 + lane)*8 + e
//   holds M[mi*16 + (lane&15)][kstep*32 + (lane>>4)*8 + e]
// ---------------------------------------------------------------------------
__global__ __launch_bounds__(128) void finalize_kernel(
    const float* __restrict__ G, const float* __restrict__ gamma,
    const float* __restrict__ omega, const float* __restrict__ conv_w,
    ushort* __restrict__ Mtf)
{
    __shared__ float attn[2][64][64];
    const int b = blockIdx.x;
    const int t = threadIdx.x;
    const float gam = gamma[0], om = omega[0];
    {
        const int map = t >> 6, i = t & 63;
        const float need = (map == 0) ? om : gam;
        if (need != 0.f) {
            const float* Grow = G + ((size_t)(b * 2 + map) << 12) + i * 64;
            float mn = Grow[0];
            for (int j = 1; j < 64; ++j) mn = fminf(mn, Grow[j]);
            float s = 0.f;
            for (int j = 0; j < 64; ++j) s += expf(mn - Grow[j]);
            const float inv = 1.f / s;
            for (int j = 0; j < 64; ++j) attn[map][i][j] = expf(mn - Grow[j]) * inv;
        }
    }
    __syncthreads();
    for (int idx = t; idx < 8192; idx += 128) {
        const int e     = idx & 7;
        const int l     = (idx >> 3) & 63;
        const int mi    = (idx >> 9) & 3;
        const int kstep = idx >> 11;
        const int row = mi * 16 + (l & 15);
        const int k   = kstep * 32 + (l >> 4) * 8 + e;
        const float* wrow = conv_w + row * TWOC;
        float v = wrow[k];
        if (k < 64) {
            if (gam != 0.f) {
                float dot = 0.f;
                for (int c = 0; c < 64; ++c) dot += wrow[c] * attn[1][c][k];      // r_attn
                v += gam * dot;
            }
        } else {
            const int d = k - 64;
            if (om != 0.f) {
                float dot = 0.f;
                for (int c = 0; c < 64; ++c) dot += wrow[64 + c] * attn[0][c][d]; // t_attn
                v += om * dot;
            }
        }
        Mtf[(size_t)b * 8192 + idx] = f2bf(v);
    }
}

// ---------------------------------------------------------------------------
// Kernel 3 (MFMA + double-buffered DMA pipeline, counted vmcnt):
//   out[b](64 x 16384) = M[b](64x128) @ X(128x16384) + bias
// X rows 0..63 = template channels, 64..127 = roi channels.
//
// T3/T4 minimum-2-phase recipe: Xs[2][32][256] f32 ping-pong (64 KB), raw
// s_barrier + counted s_waitcnt vmcnt(12) -- the memory queue NEVER empties
// (while computing chunk c, chunk c+1's 32 KB is fully queued; c+2 queues
// right after the read-release barrier). Per wave per chunk: 8 independent
// global_load_lds_dwordx4 (1 KB px-rows) + 4 A-frag dwordx4 (L2-hot),
// so outstanding-after-wait = 8+4 = 12 exactly.
// Compute: B-frags = 8 ds_read_b32 + read-side f32->bf16 pack; 16 MFMA.
// Epilogue: direct dword stores (historically clean 65.5 MB WRITE).
// __launch_bounds__(256,2): 2 blocks/CU (LDS-bound), 256-reg cap -> no spill.
// Grid 64x16 = 1024 blocks = exactly 2/CU, single residency round.
// ---------------------------------------------------------------------------
__global__ __launch_bounds__(256, 2) void out_kernel(
    const float* __restrict__ tmap, const float* __restrict__ rmap,
    const ushort* __restrict__ Mtf, const float* __restrict__ conv_b,
    float* __restrict__ out)
{
    __shared__ __align__(16) uint Xs[2][32][256];   // 64 KB ping-pong

    const int b   = blockIdx.y;
    const int t   = threadIdx.x;
    const int w   = t >> 6;
    const int l   = t & 63;
    const int lg  = l >> 4;
    const int lj  = l & 15;
    const int px0 = blockIdx.x * 256;

    const ushort* mbase = Mtf + (size_t)b * 8192;
    const float*  tb = tmap + (size_t)b * CH * NPIX + px0;
    const float*  rb = rmap + (size_t)b * CH * NPIX + px0;

    // chunk c covers global k = c*32 .. c*32+31; c<2: template rows, else roi
#define SRC(c) (((c) < 2 ? tb : rb) + (size_t)(((c) & 1) * 32) * NPIX)

    // ---- prologue: queue chunks 0 and 1 (DMA + A-frags, 12 vm-ops each) ----
    short8 a[2][4];
#pragma unroll
    for (int i = 0; i < 8; ++i) {
        const int row = i * 4 + w;
        gload16(SRC(0) + (size_t)row * NPIX + 4 * l, &Xs[0][row][0]);
    }
#pragma unroll
    for (int mi = 0; mi < 4; ++mi)
        a[0][mi] = *(const short8*)&mbase[((0 * 4 + mi) * 64 + l) * 8];
#pragma unroll
    for (int i = 0; i < 8; ++i) {
        const int row = i * 4 + w;
        gload16(SRC(1) + (size_t)row * NPIX + 4 * l, &Xs[1][row][0]);
    }
#pragma unroll
    for (int mi = 0; mi < 4; ++mi)
        a[1][mi] = *(const short8*)&mbase[((1 * 4 + mi) * 64 + l) * 8];

    floatx4 acc[4][4];
#pragma unroll
    for (int mi = 0; mi < 4; ++mi)
#pragma unroll
        for (int nj = 0; nj < 4; ++nj) acc[mi][nj] = (floatx4){0.f, 0.f, 0.f, 0.f};

#pragma unroll
    for (int c = 0; c < 4; ++c) {
        // wait own chunk-c loads (12 younger stay in flight), then sync block
        if (c < 3) { asm volatile("s_waitcnt vmcnt(12)" ::: "memory"); }
        else       { asm volatile("s_waitcnt vmcnt(0)"  ::: "memory"); }
        __builtin_amdgcn_sched_barrier(0);
        __builtin_amdgcn_s_barrier();            // all waves' chunk-c DMA done
        __builtin_amdgcn_sched_barrier(0);

        // compute chunk c from Xs[c&1]
#pragma unroll
        for (int nj = 0; nj < 4; ++nj) {
            const int pxl = w * 64 + nj * 16 + lj;
            float v[8];
#pragma unroll
            for (int e = 0; e < 8; ++e)
                v[e] = __uint_as_float(Xs[c & 1][8 * lg + e][pxl]);
            uint4 bu;
            bu.x = pk2(v[0], v[1]);
            bu.y = pk2(v[2], v[3]);
            bu.z = pk2(v[4], v[5]);
            bu.w = pk2(v[6], v[7]);
            const short8 bb = *(const short8*)&bu;
#pragma unroll
            for (int mi = 0; mi < 4; ++mi)
                acc[mi][nj] = __builtin_amdgcn_mfma_f32_16x16x32_bf16(
                    a[c & 1][mi], bb, acc[mi][nj], 0, 0, 0);
        }

        // release buffer: all reads complete across the block
        asm volatile("s_waitcnt lgkmcnt(0)" ::: "memory");
        __builtin_amdgcn_sched_barrier(0);
        __builtin_amdgcn_s_barrier();
        __builtin_amdgcn_sched_barrier(0);

        // refill the just-released buffer with chunk c+2 (keeps queue full)
        if (c < 2) {
            const int cn = c + 2;
#pragma unroll
            for (int i = 0; i < 8; ++i) {
                const int row = i * 4 + w;
                gload16(SRC(cn) + (size_t)row * NPIX + 4 * l, &Xs[c & 1][row][0]);
            }
#pragma unroll
            for (int mi = 0; mi < 4; ++mi)
                a[c & 1][mi] = *(const short8*)&mbase[((cn * 4 + mi) * 64 + l) * 8];
        }
    }
#undef SRC

    // epilogue: C/D layout col=lane&15, row=(lane>>4)*4+reg (guide m89/m91)
    const int pxw = px0 + w * 64;
#pragma unroll
    for (int mi = 0; mi < 4; ++mi) {
#pragma unroll
        for (int r = 0; r < 4; ++r) {
            const int och = mi * 16 + lg * 4 + r;
            const float bv = conv_b[och];
            float* orow = out + ((size_t)b * CH + och) * NPIX;
#pragma unroll
            for (int nj = 0; nj < 4; ++nj)
                orow[pxw + nj * 16 + lj] = acc[mi][nj][r] + bv;
        }
    }
}

// ---------------------------------------------------------------------------
extern "C" void kernel_launch(void* const* d_in, const int* in_sizes, int n_in,
                              void* d_out, int out_size, void* d_ws, size_t ws_size,
                              hipStream_t stream) {
    const float* tmap   = (const float*)d_in[0];
    const float* rmap   = (const float*)d_in[1];
    const float* gamma  = (const float*)d_in[2];
    const float* omega  = (const float*)d_in[3];
    const float* conv_w = (const float*)d_in[4];
    const float* conv_b = (const float*)d_in[5];
    float* out = (float*)d_out;

    // ws layout: G [16][2][4096] fp32 (512 KiB), then Mtf [16][8192] bf16 (256 KiB)
    float*  G   = (float*)d_ws;
    ushort* Mtf = (ushort*)((char*)d_ws + (size_t)BATCH * 2 * 4096 * sizeof(float));

    hipMemsetAsync(d_ws, 0, (size_t)BATCH * 2 * 4096 * sizeof(float), stream);

    gram_kernel<<<dim3(32, 2, BATCH), 256, 0, stream>>>(tmap, rmap, gamma, omega, G);
    finalize_kernel<<<dim3(BATCH), 128, 0, stream>>>(G, gamma, omega, conv_w, Mtf);
    out_kernel<<<dim3(64, BATCH), 256, 0, stream>>>(tmap, rmap, Mtf, conv_b, out);
}

// Round 11
// 53.943 us; speedup vs baseline: 1.2705x; 1.0334x over previous
//
#include <hip/hip_runtime.h>

typedef __attribute__((ext_vector_type(8))) short short8;
typedef __attribute__((ext_vector_type(4))) float floatx4;
typedef unsigned int uint;
typedef unsigned short ushort;

#define BATCH 16
#define CH 64
#define NPIX 16384   // 128*128
#define TWOC 128

__device__ __forceinline__ ushort f2bf(float f) {   // RNE f32 -> bf16 bits
    uint u = __float_as_uint(f);
    u += 0x7FFFu + ((u >> 16) & 1u);
    return (ushort)(u >> 16);
}
__device__ __forceinline__ uint pk2(float lo, float hi) {
    return (uint)f2bf(lo) | ((uint)f2bf(hi) << 16);
}

// async global->LDS DMA, 16B per lane (dest = wave-uniform base + lane*16)
typedef const __attribute__((address_space(1))) void gas_void;
typedef __attribute__((address_space(3))) void las_void;
__device__ __forceinline__ void gload16(const void* g, void* l) {
    __builtin_amdgcn_global_load_lds((gas_void*)g, (las_void*)l, 16, 0, 0);
}

// ---------------------------------------------------------------------------
// Kernel 1: partial Gram matrices G[b][map][64][64] = sum_n V[c,n]*V[d,n]
// Early-exits when the corresponding scalar is exactly 0 (algebraic
// short-circuit: contribution is exactly zero; still deterministic).
// ---------------------------------------------------------------------------
__global__ __launch_bounds__(256) void gram_kernel(
    const float* __restrict__ tmap, const float* __restrict__ rmap,
    const float* __restrict__ gamma, const float* __restrict__ omega,
    float* __restrict__ G)
{
    const int map = blockIdx.y;
    const float mult = (map == 0) ? omega[0] : gamma[0];
    if (mult == 0.f) return;   // wave-uniform: skip dead attention branch

    __shared__ float tile[64][68];
    const int chunk = blockIdx.x;
    const int b     = blockIdx.z;
    const float* x = (map == 0 ? tmap : rmap) + (size_t)b * CH * NPIX + chunk * 512;
    const int t  = threadIdx.x;
    const int ti = t >> 4;
    const int tj = t & 15;

    float acc[4][4];
#pragma unroll
    for (int i = 0; i < 4; ++i)
#pragma unroll
        for (int j = 0; j < 4; ++j) acc[i][j] = 0.f;

    for (int tt = 0; tt < 8; ++tt) {
        const int col0 = tt * 64;
#pragma unroll
        for (int k = 0; k < 16; ++k) {
            int e = t + 256 * k;
            int c = e >> 6, col = e & 63;
            tile[c][col] = x[(size_t)c * NPIX + col0 + col];
        }
        __syncthreads();
#pragma unroll 8
        for (int n = 0; n < 64; n += 2) {
            float2 av[4], bv[4];
#pragma unroll
            for (int i = 0; i < 4; ++i) av[i] = *(const float2*)&tile[ti + 16 * i][n];
#pragma unroll
            for (int j = 0; j < 4; ++j) bv[j] = *(const float2*)&tile[tj + 16 * j][n];
#pragma unroll
            for (int i = 0; i < 4; ++i)
#pragma unroll
                for (int j = 0; j < 4; ++j) {
                    acc[i][j] += av[i].x * bv[j].x;
                    acc[i][j] += av[i].y * bv[j].y;
                }
        }
        __syncthreads();
    }
    float* Gp = G + ((size_t)(b * 2 + map) << 12);
#pragma unroll
    for (int i = 0; i < 4; ++i)
#pragma unroll
        for (int j = 0; j < 4; ++j)
            atomicAdd(&Gp[(ti + 16 * i) * 64 + (tj + 16 * j)], acc[i][j]);
}

// ---------------------------------------------------------------------------
// Kernel 2: per-batch softmax + build mixing matrix, stored as bf16
// A-FRAGMENTS for mfma_f32_16x16x32_bf16:
//   flat idx = ((kstep*4 + mi)*64 + lane)*8 + e
//   holds M[mi*16 + (lane&15)][kstep*32 + (lane>>4)*8 + e]
// ---------------------------------------------------------------------------
__global__ __launch_bounds__(128) void finalize_kernel(
    const float* __restrict__ G, const float* __restrict__ gamma,
    const float* __restrict__ omega, const float* __restrict__ conv_w,
    ushort* __restrict__ Mtf)
{
    __shared__ float attn[2][64][64];
    const int b = blockIdx.x;
    const int t = threadIdx.x;
    const float gam = gamma[0], om = omega[0];
    {
        const int map = t >> 6, i = t & 63;
        const float need = (map == 0) ? om : gam;
        if (need != 0.f) {
            const float* Grow = G + ((size_t)(b * 2 + map) << 12) + i * 64;
            float mn = Grow[0];
            for (int j = 1; j < 64; ++j) mn = fminf(mn, Grow[j]);
            float s = 0.f;
            for (int j = 0; j < 64; ++j) s += expf(mn - Grow[j]);
            const float inv = 1.f / s;
            for (int j = 0; j < 64; ++j) attn[map][i][j] = expf(mn - Grow[j]) * inv;
        }
    }
    __syncthreads();
    for (int idx = t; idx < 8192; idx += 128) {
        const int e     = idx & 7;
        const int l     = (idx >> 3) & 63;
        const int mi    = (idx >> 9) & 3;
        const int kstep = idx >> 11;
        const int row = mi * 16 + (l & 15);
        const int k   = kstep * 32 + (l >> 4) * 8 + e;
        const float* wrow = conv_w + row * TWOC;
        float v = wrow[k];
        if (k < 64) {
            if (gam != 0.f) {
                float dot = 0.f;
                for (int c = 0; c < 64; ++c) dot += wrow[c] * attn[1][c][k];      // r_attn
                v += gam * dot;
            }
        } else {
            const int d = k - 64;
            if (om != 0.f) {
                float dot = 0.f;
                for (int c = 0; c < 64; ++c) dot += wrow[64 + c] * attn[0][c][d]; // t_attn
                v += om * dot;
            }
        }
        Mtf[(size_t)b * 8192 + idx] = f2bf(v);
    }
}

// ---------------------------------------------------------------------------
// Kernel 3 (MFMA + double-buffered DMA pipeline + chunked XCD swizzle):
//   out[b](64 x 16384) = M[b](64x128) @ X(128x16384) + bias
// X rows 0..63 = template channels, 64..127 = roi channels.
//
// Identical pipeline to r10 (Xs[2][32][256] ping-pong, counted vmcnt(12),
// raw s_barrier, DMA global_load_lds 1KB rows, direct stores). ONE change:
// flat 1D grid with chunked XCD swizzle (T1). HW round-robins blockIdx over
// the 8 XCDs; we invert that so XCD x owns work-ids [x*128,(x+1)*128) =
// 2 full batches swept px-major. Co-resident blocks of an XCD then read a
// CONTIGUOUS 64KB window of each row through one L2 (dense linear sweep of
// a 64MB region per XCD) instead of scattering 1KB granules across all 8
// L2s -- the DRAM/routing-pattern lever, the last untried first-order one.
// ---------------------------------------------------------------------------
__global__ __launch_bounds__(256, 2) void out_kernel(
    const float* __restrict__ tmap, const float* __restrict__ rmap,
    const ushort* __restrict__ Mtf, const float* __restrict__ conv_b,
    float* __restrict__ out)
{
    __shared__ __align__(16) uint Xs[2][32][256];   // 64 KB ping-pong

    // chunked XCD swizzle: hw id -> (xcd = hw&7) owns contiguous wid chunk
    const int hw  = blockIdx.x;          // 0..1023, round-robin over XCDs
    const int wid = (hw & 7) * 128 + (hw >> 3);
    const int b   = wid >> 6;            // batch
    const int px0 = (wid & 63) * 256;    // px chunk, swept in order per XCD

    const int t   = threadIdx.x;
    const int w   = t >> 6;
    const int l   = t & 63;
    const int lg  = l >> 4;
    const int lj  = l & 15;

    const ushort* mbase = Mtf + (size_t)b * 8192;
    const float*  tb = tmap + (size_t)b * CH * NPIX + px0;
    const float*  rb = rmap + (size_t)b * CH * NPIX + px0;

    // chunk c covers global k = c*32 .. c*32+31; c<2: template rows, else roi
#define SRC(c) (((c) < 2 ? tb : rb) + (size_t)(((c) & 1) * 32) * NPIX)

    // ---- prologue: queue chunks 0 and 1 (DMA + A-frags, 12 vm-ops each) ----
    short8 a[2][4];
#pragma unroll
    for (int i = 0; i < 8; ++i) {
        const int row = i * 4 + w;
        gload16(SRC(0) + (size_t)row * NPIX + 4 * l, &Xs[0][row][0]);
    }
#pragma unroll
    for (int mi = 0; mi < 4; ++mi)
        a[0][mi] = *(const short8*)&mbase[((0 * 4 + mi) * 64 + l) * 8];
#pragma unroll
    for (int i = 0; i < 8; ++i) {
        const int row = i * 4 + w;
        gload16(SRC(1) + (size_t)row * NPIX + 4 * l, &Xs[1][row][0]);
    }
#pragma unroll
    for (int mi = 0; mi < 4; ++mi)
        a[1][mi] = *(const short8*)&mbase[((1 * 4 + mi) * 64 + l) * 8];

    floatx4 acc[4][4];
#pragma unroll
    for (int mi = 0; mi < 4; ++mi)
#pragma unroll
        for (int nj = 0; nj < 4; ++nj) acc[mi][nj] = (floatx4){0.f, 0.f, 0.f, 0.f};

#pragma unroll
    for (int c = 0; c < 4; ++c) {
        // wait own chunk-c loads (12 younger stay in flight), then sync block
        if (c < 3) { asm volatile("s_waitcnt vmcnt(12)" ::: "memory"); }
        else       { asm volatile("s_waitcnt vmcnt(0)"  ::: "memory"); }
        __builtin_amdgcn_sched_barrier(0);
        __builtin_amdgcn_s_barrier();            // all waves' chunk-c DMA done
        __builtin_amdgcn_sched_barrier(0);

        // compute chunk c from Xs[c&1]
#pragma unroll
        for (int nj = 0; nj < 4; ++nj) {
            const int pxl = w * 64 + nj * 16 + lj;
            float v[8];
#pragma unroll
            for (int e = 0; e < 8; ++e)
                v[e] = __uint_as_float(Xs[c & 1][8 * lg + e][pxl]);
            uint4 bu;
            bu.x = pk2(v[0], v[1]);
            bu.y = pk2(v[2], v[3]);
            bu.z = pk2(v[4], v[5]);
            bu.w = pk2(v[6], v[7]);
            const short8 bb = *(const short8*)&bu;
#pragma unroll
            for (int mi = 0; mi < 4; ++mi)
                acc[mi][nj] = __builtin_amdgcn_mfma_f32_16x16x32_bf16(
                    a[c & 1][mi], bb, acc[mi][nj], 0, 0, 0);
        }

        // release buffer: all reads complete across the block
        asm volatile("s_waitcnt lgkmcnt(0)" ::: "memory");
        __builtin_amdgcn_sched_barrier(0);
        __builtin_amdgcn_s_barrier();
        __builtin_amdgcn_sched_barrier(0);

        // refill the just-released buffer with chunk c+2 (keeps queue full)
        if (c < 2) {
            const int cn = c + 2;
#pragma unroll
            for (int i = 0; i < 8; ++i) {
                const int row = i * 4 + w;
                gload16(SRC(cn) + (size_t)row * NPIX + 4 * l, &Xs[c & 1][row][0]);
            }
#pragma unroll
            for (int mi = 0; mi < 4; ++mi)
                a[c & 1][mi] = *(const short8*)&mbase[((cn * 4 + mi) * 64 + l) * 8];
        }
    }
#undef SRC

    // epilogue: C/D layout col=lane&15, row=(lane>>4)*4+reg (guide m89/m91)
    const int pxw = px0 + w * 64;
#pragma unroll
    for (int mi = 0; mi < 4; ++mi) {
#pragma unroll
        for (int r = 0; r < 4; ++r) {
            const int och = mi * 16 + lg * 4 + r;
            const float bv = conv_b[och];
            float* orow = out + ((size_t)b * CH + och) * NPIX;
#pragma unroll
            for (int nj = 0; nj < 4; ++nj)
                orow[pxw + nj * 16 + lj] = acc[mi][nj][r] + bv;
        }
    }
}

// ---------------------------------------------------------------------------
extern "C" void kernel_launch(void* const* d_in, const int* in_sizes, int n_in,
                              void* d_out, int out_size, void* d_ws, size_t ws_size,
                              hipStream_t stream) {
    const float* tmap   = (const float*)d_in[0];
    const float* rmap   = (const float*)d_in[1];
    const float* gamma  = (const float*)d_in[2];
    const float* omega  = (const float*)d_in[3];
    const float* conv_w = (const float*)d_in[4];
    const float* conv_b = (const float*)d_in[5];
    float* out = (float*)d_out;

    // ws layout: G [16][2][4096] fp32 (512 KiB), then Mtf [16][8192] bf16 (256 KiB)
    float*  G   = (float*)d_ws;
    ushort* Mtf = (ushort*)((char*)d_ws + (size_t)BATCH * 2 * 4096 * sizeof(float));

    hipMemsetAsync(d_ws, 0, (size_t)BATCH * 2 * 4096 * sizeof(float), stream);

    gram_kernel<<<dim3(32, 2, BATCH), 256, 0, stream>>>(tmap, rmap, gamma, omega, G);
    finalize_kernel<<<dim3(BATCH), 128, 0, stream>>>(G, gamma, omega, conv_w, Mtf);
    out_kernel<<<dim3(1024), 256, 0, stream>>>(tmap, rmap, Mtf, conv_b, out);
}

// Round 12
// 45.813 us; speedup vs baseline: 1.4960x; 1.1775x over previous
//
#include <hip/hip_runtime.h>

typedef __attribute__((ext_vector_type(8))) short short8;
typedef __attribute__((ext_vector_type(4))) float floatx4;
typedef unsigned int uint;
typedef unsigned short ushort;

#define BATCH 16
#define CH 64
#define NPIX 16384   // 128*128
#define TWOC 128

__device__ __forceinline__ ushort f2bf(float f) {   // RNE f32 -> bf16 bits
    uint u = __float_as_uint(f);
    u += 0x7FFFu + ((u >> 16) & 1u);
    return (ushort)(u >> 16);
}
__device__ __forceinline__ uint pk2(float lo, float hi) {
    return (uint)f2bf(lo) | ((uint)f2bf(hi) << 16);
}

// async global->LDS DMA, 16B per lane (dest = wave-uniform base + lane*16)
typedef const __attribute__((address_space(1))) void gas_void;
typedef __attribute__((address_space(3))) void las_void;
__device__ __forceinline__ void gload16(const void* g, void* l) {
    __builtin_amdgcn_global_load_lds((gas_void*)g, (las_void*)l, 16, 0, 0);
}

// ---------------------------------------------------------------------------
// Kernel 1: partial Gram matrices G[b][map][64][64] = sum_n V[c,n]*V[d,n]
// map 0 = template (t_attn, needed iff omega!=0); map 1 = roi (r_attn, iff
// gamma!=0). Early-exits when the multiplier is exactly 0 (contribution is
// exactly zero -- algebraic short-circuit, deterministic).
// ---------------------------------------------------------------------------
__global__ __launch_bounds__(256) void gram_kernel(
    const float* __restrict__ tmap, const float* __restrict__ rmap,
    const float* __restrict__ gamma, const float* __restrict__ omega,
    float* __restrict__ G)
{
    const int map = blockIdx.y;
    const float mult = (map == 0) ? omega[0] : gamma[0];
    if (mult == 0.f) return;

    __shared__ float tile[64][68];
    const int chunk = blockIdx.x;
    const int b     = blockIdx.z;
    const float* x = (map == 0 ? tmap : rmap) + (size_t)b * CH * NPIX + chunk * 512;
    const int t  = threadIdx.x;
    const int ti = t >> 4;
    const int tj = t & 15;

    float acc[4][4];
#pragma unroll
    for (int i = 0; i < 4; ++i)
#pragma unroll
        for (int j = 0; j < 4; ++j) acc[i][j] = 0.f;

    for (int tt = 0; tt < 8; ++tt) {
        const int col0 = tt * 64;
#pragma unroll
        for (int k = 0; k < 16; ++k) {
            int e = t + 256 * k;
            int c = e >> 6, col = e & 63;
            tile[c][col] = x[(size_t)c * NPIX + col0 + col];
        }
        __syncthreads();
#pragma unroll 8
        for (int n = 0; n < 64; n += 2) {
            float2 av[4], bv[4];
#pragma unroll
            for (int i = 0; i < 4; ++i) av[i] = *(const float2*)&tile[ti + 16 * i][n];
#pragma unroll
            for (int j = 0; j < 4; ++j) bv[j] = *(const float2*)&tile[tj + 16 * j][n];
#pragma unroll
            for (int i = 0; i < 4; ++i)
#pragma unroll
                for (int j = 0; j < 4; ++j) {
                    acc[i][j] += av[i].x * bv[j].x;
                    acc[i][j] += av[i].y * bv[j].y;
                }
        }
        __syncthreads();
    }
    float* Gp = G + ((size_t)(b * 2 + map) << 12);
#pragma unroll
    for (int i = 0; i < 4; ++i)
#pragma unroll
        for (int j = 0; j < 4; ++j)
            atomicAdd(&Gp[(ti + 16 * i) * 64 + (tj + 16 * j)], acc[i][j]);
}

// ---------------------------------------------------------------------------
// Kernel 2 (FUSED finalize + MFMA GEMM):
//   out[b](64 x 16384) = M[b](64x128) @ X(128x16384) + bias
//   M[o][k] = conv_w[o][k] + (k<64 ? gamma*(W1@r_attn)[o][k]
//                                  : omega*(W2@t_attn)[o][k-64])
// M is built PER BLOCK into LDS as bf16 A-fragments (zero path: straight
// repack of conv_w, ~1us redundant across blocks; nonzero path: in-block
// softmax of G (staged in Xs before DMA starts) + 64-dots). This deletes the
// finalize dispatch and the Mtf ws round-trip; A-frags hoist to registers.
// Pipeline: Xs[2][32][256] f32 ping-pong, DMA global_load_lds 1KB px-rows,
// counted s_waitcnt vmcnt(8) (DMA-only queue now), raw s_barrier, direct
// dword stores. LDS 80KB -> 2 blocks/CU. Grid 64x16, 256 thr = 4 waves.
// ---------------------------------------------------------------------------
__global__ __launch_bounds__(256, 2) void out_kernel(
    const float* __restrict__ tmap, const float* __restrict__ rmap,
    const float* __restrict__ G, const float* __restrict__ gamma,
    const float* __restrict__ omega, const float* __restrict__ conv_w,
    const float* __restrict__ conv_b, float* __restrict__ out)
{
    __shared__ __align__(16) uint   Xs[2][32][256];   // 64 KB ping-pong
    __shared__ __align__(16) ushort Ms[8192];         // 16 KB A-fragments

    const int b   = blockIdx.y;
    const int t   = threadIdx.x;
    const int w   = t >> 6;
    const int l   = t & 63;
    const int lg  = l >> 4;
    const int lj  = l & 15;
    const int px0 = blockIdx.x * 256;

    const float gam = gamma[0], om = omega[0];

    // ---- build M fragments in LDS ----
    if (gam != 0.f || om != 0.f) {
        // stage attn[2][64][64] f32 in Xs (before any DMA touches Xs)
        float* attnf = (float*)&Xs[0][0][0];
        if (t < 128) {
            const int map = t >> 6, i = t & 63;
            const float need = (map == 0) ? om : gam;
            if (need != 0.f) {
                const float* Grow = G + ((size_t)(b * 2 + map) << 12) + i * 64;
                float mn = Grow[0];
                for (int j = 1; j < 64; ++j) mn = fminf(mn, Grow[j]);
                float s = 0.f;
                for (int j = 0; j < 64; ++j) s += expf(mn - Grow[j]);
                const float inv = 1.f / s;
                for (int j = 0; j < 64; ++j)
                    attnf[(map << 12) + i * 64 + j] = expf(mn - Grow[j]) * inv;
            }
        }
        __syncthreads();
#pragma unroll
        for (int j = 0; j < 32; ++j) {
            const int idx = t + 256 * j;
            const int e = idx & 7, ll = (idx >> 3) & 63;
            const int mi = (idx >> 9) & 3, kstep = idx >> 11;
            const int row = mi * 16 + (ll & 15);
            const int k   = kstep * 32 + (ll >> 4) * 8 + e;
            const float* wrow = conv_w + row * TWOC;
            float v = wrow[k];
            if (k < 64) {
                if (gam != 0.f) {
                    float dot = 0.f;
                    for (int c = 0; c < 64; ++c) dot += wrow[c] * attnf[(1 << 12) + c * 64 + k];
                    v += gam * dot;
                }
            } else {
                if (om != 0.f) {
                    float dot = 0.f;
                    for (int c = 0; c < 64; ++c) dot += wrow[64 + c] * attnf[c * 64 + (k - 64)];
                    v += om * dot;
                }
            }
            Ms[idx] = f2bf(v);
        }
        __syncthreads();   // attn reads done; Xs free for DMA; Ms visible
    } else {
        // zero path: M == conv_w, straight repack (no attn, no G)
#pragma unroll
        for (int j = 0; j < 32; ++j) {
            const int idx = t + 256 * j;
            const int e = idx & 7, ll = (idx >> 3) & 63;
            const int mi = (idx >> 9) & 3, kstep = idx >> 11;
            const int row = mi * 16 + (ll & 15);
            const int k   = kstep * 32 + (ll >> 4) * 8 + e;
            Ms[idx] = f2bf(conv_w[row * TWOC + k]);
        }
        // Ms visibility handled by the pre-loop lgkm+barrier below
    }

    const float* tb = tmap + (size_t)b * CH * NPIX + px0;
    const float* rb = rmap + (size_t)b * CH * NPIX + px0;
#define SRC(c) (((c) < 2 ? tb : rb) + (size_t)(((c) & 1) * 32) * NPIX)

    // ---- prologue: queue chunks 0 and 1 (8 DMA ops each; vm queue = DMA only) ----
#pragma unroll
    for (int i = 0; i < 8; ++i) {
        const int row = i * 4 + w;
        gload16(SRC(0) + (size_t)row * NPIX + 4 * l, &Xs[0][row][0]);
    }
#pragma unroll
    for (int i = 0; i < 8; ++i) {
        const int row = i * 4 + w;
        gload16(SRC(1) + (size_t)row * NPIX + 4 * l, &Xs[1][row][0]);
    }

    // Ms visible to all waves (drain own LDS ops, then block barrier)
    asm volatile("s_waitcnt lgkmcnt(0)" ::: "memory");
    __builtin_amdgcn_s_barrier();
    __builtin_amdgcn_sched_barrier(0);

    // hoist all A-fragments to registers (16 x ds_read_b128, stable all loop)
    short8 a[4][4];
#pragma unroll
    for (int c = 0; c < 4; ++c)
#pragma unroll
        for (int mi = 0; mi < 4; ++mi)
            a[c][mi] = *(const short8*)&Ms[((c * 4 + mi) * 64 + l) * 8];

    floatx4 acc[4][4];
#pragma unroll
    for (int mi = 0; mi < 4; ++mi)
#pragma unroll
        for (int nj = 0; nj < 4; ++nj) acc[mi][nj] = (floatx4){0.f, 0.f, 0.f, 0.f};

#pragma unroll
    for (int c = 0; c < 4; ++c) {
        // wait own chunk-c DMA (chunk c+1's 8 ops stay in flight), sync block
        if (c < 3) { asm volatile("s_waitcnt vmcnt(8) lgkmcnt(0)" ::: "memory"); }
        else       { asm volatile("s_waitcnt vmcnt(0) lgkmcnt(0)" ::: "memory"); }
        __builtin_amdgcn_sched_barrier(0);
        __builtin_amdgcn_s_barrier();
        __builtin_amdgcn_sched_barrier(0);

        // compute chunk c from Xs[c&1]
#pragma unroll
        for (int nj = 0; nj < 4; ++nj) {
            const int pxl = w * 64 + nj * 16 + lj;
            float v[8];
#pragma unroll
            for (int e = 0; e < 8; ++e)
                v[e] = __uint_as_float(Xs[c & 1][8 * lg + e][pxl]);
            uint4 bu;
            bu.x = pk2(v[0], v[1]);
            bu.y = pk2(v[2], v[3]);
            bu.z = pk2(v[4], v[5]);
            bu.w = pk2(v[6], v[7]);
            const short8 bb = *(const short8*)&bu;
#pragma unroll
            for (int mi = 0; mi < 4; ++mi)
                acc[mi][nj] = __builtin_amdgcn_mfma_f32_16x16x32_bf16(
                    a[c][mi], bb, acc[mi][nj], 0, 0, 0);
        }

        // release buffer: all reads complete across the block
        asm volatile("s_waitcnt lgkmcnt(0)" ::: "memory");
        __builtin_amdgcn_sched_barrier(0);
        __builtin_amdgcn_s_barrier();
        __builtin_amdgcn_sched_barrier(0);

        // refill the just-released buffer with chunk c+2
        if (c < 2) {
            const int cn = c + 2;
#pragma unroll
            for (int i = 0; i < 8; ++i) {
                const int row = i * 4 + w;
                gload16(SRC(cn) + (size_t)row * NPIX + 4 * l, &Xs[c & 1][row][0]);
            }
        }
    }
#undef SRC

    // epilogue: C/D layout col=lane&15, row=(lane>>4)*4+reg (guide m89/m91)
    const int pxw = px0 + w * 64;
#pragma unroll
    for (int mi = 0; mi < 4; ++mi) {
#pragma unroll
        for (int r = 0; r < 4; ++r) {
            const int och = mi * 16 + lg * 4 + r;
            const float bv = conv_b[och];
            float* orow = out + ((size_t)b * CH + och) * NPIX;
#pragma unroll
            for (int nj = 0; nj < 4; ++nj)
                orow[pxw + nj * 16 + lj] = acc[mi][nj][r] + bv;
        }
    }
}

// ---------------------------------------------------------------------------
extern "C" void kernel_launch(void* const* d_in, const int* in_sizes, int n_in,
                              void* d_out, int out_size, void* d_ws, size_t ws_size,
                              hipStream_t stream) {
    const float* tmap   = (const float*)d_in[0];
    const float* rmap   = (const float*)d_in[1];
    const float* gamma  = (const float*)d_in[2];
    const float* omega  = (const float*)d_in[3];
    const float* conv_w = (const float*)d_in[4];
    const float* conv_b = (const float*)d_in[5];
    float* out = (float*)d_out;

    // ws layout: G [16][2][4096] fp32 (512 KiB)
    float* G = (float*)d_ws;

    hipMemsetAsync(d_ws, 0, (size_t)BATCH * 2 * 4096 * sizeof(float), stream);

    gram_kernel<<<dim3(32, 2, BATCH), 256, 0, stream>>>(tmap, rmap, gamma, omega, G);
    out_kernel<<<dim3(64, BATCH), 256, 0, stream>>>(tmap, rmap, G, gamma, omega,
                                                    conv_w, conv_b, out);
}